// Round 15
// baseline (832.971 us; speedup 1.0000x reference)
//
#include <hip/hip_runtime.h>
#include <math.h>

#define NN 1024
#define NNP 1025
#define DD 256
#define CC 5
#define G3 768
#define MAXT 512
#define NA 70
#define NGRU 10

typedef _Float16 v8h __attribute__((ext_vector_type(8)));
typedef _Float16 v4h __attribute__((ext_vector_type(4)));
typedef float v4f __attribute__((ext_vector_type(4)));
typedef int v4i __attribute__((ext_vector_type(4)));

#define NF1 (3*16*17*64)
#define NF2 (3*16*8*64)
#define NF3 (3*11*8*64)
#define NFT (NF1+NF2+NF3)

__device__ __forceinline__ float sigf(float x){ return __fdividef(1.f, 1.f + __expf(-x)); }
__device__ __forceinline__ float tanhf_fast(float x){ return 1.f - __fdividef(2.f, __expf(2.f*x) + 1.f); }

// ================= MEGA kernel (unchanged from round 14) =================
__global__ __launch_bounds__(256) void mega_kernel(
    const float* __restrict__ node_pred, const float* __restrict__ tp_in,
    const float* __restrict__ audio_len, const float* __restrict__ anchors,
    const float* __restrict__ whh, const float* __restrict__ wih,
    const float* __restrict__ emb,
    const float* __restrict__ bih, const float* __restrict__ bhh,
    const float* __restrict__ w1, const float* __restrict__ w2,
    const float* __restrict__ w30, const float* __restrict__ w31, const float* __restrict__ w32,
    float* __restrict__ abn, int* __restrict__ order, int* __restrict__ cnteff,
    float* __restrict__ qs, float* __restrict__ cm,
    uint4* __restrict__ whhB8, _Float16* __restrict__ E){
  __shared__ __align__(16) unsigned char smem[16*264*2];
  int b = blockIdx.x, tid = threadIdx.x;
  if (b < 4){
    int i = b*256 + tid;
    float pv[CC]; float m = -1e30f;
    for (int c=0;c<CC;++c){ pv[c]=node_pred[i*CC+c]; m=fmaxf(m,pv[c]); }
    float s=0.f;
    for (int c=0;c<CC;++c) s += expf(pv[c]-m);
    abn[i] = expf(pv[0]-m)/s;
  } else if (b < 74){
    if (tid >= 64) return;
    int a = b-4; int lane = tid;
    float al = audio_len[0];
    float s = anchors[2*a], e = anchors[2*a+1];
    int* ord = order + a*MAXT;
    int cnt = 0;
    for (int base=0; base<NN; base+=64){
      float tp = tp_in[base+lane]*al;
      bool msk = (tp>=s)&&(tp<=e);
      unsigned long long bal = __ballot(msk);
      int off = (int)__popcll(bal & ((1ull<<lane)-1ull));
      if (msk && (cnt+off)<MAXT) ord[cnt+off] = base+lane;
      cnt += (int)__popcll(bal);
    }
    if (lane==0){ int c = cnt<MAXT?cnt:MAXT; cnteff[2*a]=c; cnteff[2*a+1]=(c>0)?c:1; }
  } else if (b < 83){
    int m = b-74;
    const float* p; int n;
    if (m<3){ p = w1 + (size_t)m*256*519; n = 256*519; }
    else if (m<6){ p = w2 + (size_t)(m-3)*256*256; n = 256*256; }
    else { p = (m==6)?w30:((m==7)?w31:w32); n = ((m==7)?125:165)*256; }
    float mx = 0.f;
    for (int i=tid;i<n;i+=256) mx = fmaxf(mx, fabsf(p[i]));
    float* red = (float*)smem;
    red[tid]=mx; __syncthreads();
    for (int sft=128; sft>0; sft>>=1){ if (tid<sft) red[tid]=fmaxf(red[tid],red[tid+sft]); __syncthreads(); }
    if (tid==0) qs[m] = fmaxf(red[0]/127.f, 1e-8f);
  } else if (b < 101){
    int i = (b-83)*256 + tid;
    if (i >= 4608) return;
    int gt = i % 3; int c = (i/3)&255; int sd = i/768;
    int j = gt*256 + c;
    float v = bih[sd*G3+j] + ((gt<2)? bhh[sd*G3+j] : 0.f);
    E[((size_t)(sd*NNP + NN))*1024 + c*4 + gt] = (_Float16)v;
  } else if (b < 149){
    int bb = b-101;
    int sd = bb>>3, w = bb&7;
    float* cm_lds = (float*)smem;
    int lane = tid & 63, wv = tid >> 6;
    for (int it=0; it<24; ++it){
      int lr = it*4 + wv;
      int gt = lr>>5, c = lr&31;
      int j = gt*256 + w*32 + c;
      float4 v = reinterpret_cast<const float4*>(whh + ((size_t)sd*G3 + j)*DD)[lane];
      float mx = fmaxf(fmaxf(fabsf(v.x),fabsf(v.y)), fmaxf(fabsf(v.z),fabsf(v.w)));
      #pragma unroll
      for (int sh=1; sh<64; sh<<=1) mx = fmaxf(mx, __shfl_xor(mx, sh));
      if (lane==0){
        float cmax = fmaxf(mx, 1e-12f);
        cm_lds[lr] = cmax;
        cm[sd*G3 + j] = cmax;
      }
    }
    __syncthreads();
    #pragma unroll
    for (int ee=0; ee<6; ++ee){
      int il = tid*6 + ee;
      int q    = il & 3;
      int nt   = (il>>2) % 6;
      int lane2= il / 24;
      int gt = nt>>1, half = nt&1;
      int j  = gt*256 + w*32 + half*16 + (lane2&15);
      int lr = gt*32  + half*16 + (lane2&15);
      int kbase = 64*q + 16*(lane2>>4);
      float inv = 127.f/cm_lds[lr];
      const float* src = whh + ((size_t)sd*G3 + j)*DD + kbase;
      unsigned int dw[4];
      #pragma unroll
      for (int d2=0; d2<4; ++d2){
        unsigned int acc = 0;
        #pragma unroll
        for (int e2=0; e2<4; ++e2){
          float qv = rintf(src[4*d2+e2]*inv);
          qv = fminf(fmaxf(qv,-127.f),127.f);
          int iq = (int)qv;
          acc |= ((unsigned int)(iq & 255)) << (8*e2);
        }
        dw[d2] = acc;
      }
      uint4 v; v.x=dw[0]; v.y=dw[1]; v.z=dw[2]; v.w=dw[3];
      whhB8[(size_t)(sd*8 + w)*1536 + il] = v;
    }
  } else {
    typedef _Float16 AsT[264];
    AsT* As = (AsT*)smem;
    int b2 = b - 149;                    // 0..575
    int sd = b2 / 96;
    int rem = b2 - sd*96;
    int cg = rem >> 3, rq = rem & 7;
    int lane = tid & 63, wv = tid >> 6;
    int l15 = lane & 15, g16 = lane >> 4;
    int c_t = cg*4 + wv;
    int j = c_t*16 + l15;
    const float* Bp = wih + ((size_t)sd*G3 + j)*DD + 8*g16;
    float bsum = bih[sd*G3 + j] + (((j>>8) < 2) ? bhh[sd*G3 + j] : 0.f);
    v8h bf[8];
    #pragma unroll
    for (int q=0;q<8;++q){
      float4 b0 = *reinterpret_cast<const float4*>(Bp + 32*q);
      float4 b1 = *reinterpret_cast<const float4*>(Bp + 32*q + 4);
      v8h o;
      o[0]=(_Float16)b0.x; o[1]=(_Float16)b0.y; o[2]=(_Float16)b0.z; o[3]=(_Float16)b0.w;
      o[4]=(_Float16)b1.x; o[5]=(_Float16)b1.y; o[6]=(_Float16)b1.z; o[7]=(_Float16)b1.w;
      bf[q] = o;
    }
    int gt = j>>8, cc = j&255;
    for (int rt8=0; rt8<8; ++rt8){
      int row0 = (rq*8 + rt8)*16;
      {
        int rr = tid>>4, k0 = (tid&15)*16;
        const float4* ep = reinterpret_cast<const float4*>(emb + (size_t)(row0+rr)*DD + k0);
        #pragma unroll
        for (int f=0; f<4; ++f){
          float4 v = ep[f];
          v4h o; o[0]=(_Float16)v.x; o[1]=(_Float16)v.y; o[2]=(_Float16)v.z; o[3]=(_Float16)v.w;
          *reinterpret_cast<v4h*>(&As[rr][k0 + f*4]) = o;
        }
      }
      __syncthreads();
      v4f acc = {0.f,0.f,0.f,0.f};
      #pragma unroll
      for (int q=0;q<8;++q){
        v8h af = *reinterpret_cast<const v8h*>(&As[l15][32*q + 8*g16]);
        acc = __builtin_amdgcn_mfma_f32_16x16x32_f16(af, bf[q], acc, 0,0,0);
      }
      #pragma unroll
      for (int r=0;r<4;++r){
        int row = row0 + g16*4 + r;
        E[((size_t)(sd*NNP + row))*1024 + cc*4 + gt] = (_Float16)(acc[r] + bsum);
      }
      __syncthreads();
    }
  }
}

// ================= GRU: M-batched (16 anchors per block, 10 blocks) + pack tail =================
__global__ __launch_bounds__(512, 2) void gru_kernel(
    const _Float16* __restrict__ E, const v4i* __restrict__ whhB8,
    const float* __restrict__ bhh, const float* __restrict__ cm,
    const int* __restrict__ order, const int* __restrict__ cnteff,
    float* __restrict__ hout,
    const float* __restrict__ w1, const float* __restrict__ w2,
    const float* __restrict__ w30, const float* __restrict__ w31, const float* __restrict__ w32,
    const float* __restrict__ qs,
    v8h* __restrict__ w1F, v8h* __restrict__ w2F, v8h* __restrict__ w3F){
  int blk = blockIdx.x;
  int tid = threadIdx.x;
  if (blk >= NGRU){
    int i = (blk - NGRU)*512 + tid;
    if (i < NF1){
      int lane = i & 63; int rest = i >> 6;
      int q = rest % 17; int rc = rest / 17;
      int ct = rc & 15; int si = rc >> 4;
      int j = ct*16 + (lane&15);
      int k0 = q*32 + 8*(lane>>4);
      float inv = 1.f/qs[si];
      const float* src = w1 + ((size_t)(si*256 + j))*519;
      v8h o;
      #pragma unroll
      for (int e=0;e<8;++e){
        int k = k0+e;
        float wv = (k<519)? src[k] : 0.f;
        float qv = rintf(wv*inv);
        qv = fminf(fmaxf(qv,-128.f),127.f);
        o[e] = (_Float16)qv;
      }
      w1F[i] = o;
    } else if (i < NF1+NF2){
      int r = i - NF1;
      int lane = r & 63; int rest = r >> 6;
      int q = rest & 7; int rc = rest >> 3;
      int ct = rc & 15; int si = rc >> 4;
      int j = ct*16 + (lane&15);
      int k0 = q*32 + 8*(lane>>4);
      float inv = 1.f/qs[3+si];
      const float* src = w2 + ((size_t)(si*256 + j))*256 + k0;
      v8h o;
      #pragma unroll
      for (int e=0;e<8;++e){
        float qv = rintf(src[e]*inv);
        qv = fminf(fmaxf(qv,-128.f),127.f);
        o[e] = (_Float16)qv;
      }
      w2F[r] = o;
    } else if (i < NFT){
      int r = i - NF1 - NF2;
      int lane = r & 63; int rest = r >> 6;
      int q = rest & 7; int rc = rest >> 3;
      int ct = rc % 11; int si = rc / 11;
      int j = ct*16 + (lane&15);
      int nout = (si==1)?125:165;
      const float* w3 = (si==0)?w30:((si==1)?w31:w32);
      int k0 = q*32 + 8*(lane>>4);
      float inv = 1.f/qs[6+si];
      v8h o;
      #pragma unroll
      for (int e=0;e<8;++e){
        float wv = (j<nout)? w3[(size_t)j*256 + k0+e] : 0.f;
        float qv = rintf(wv*inv);
        qv = fminf(fmaxf(qv,-128.f),127.f);
        o[e] = (_Float16)qv;
      }
      w3F[r] = o;
    }
    return;
  }
  // ---- GRU: blk 0..9 -> (d, si, group). 16 anchors = MFMA M rows. ----
  int d = blk & 1, q5 = blk >> 1;
  int si = (q5==0)?0:((q5<4)?1:2);
  int g  = (q5==0)?0:((q5<4)?(q5-1):0);
  int sd = si*2+d;
  int cntA = (si==1)?40:15;
  int offA = (si==0)?0:((si==1)?15:55);
  int w = tid>>6, lane = tid&63;
  int g16 = lane>>4, l15 = lane&15;

  __shared__ int ord_s[16][MAXT];                   // 32 KB
  __shared__ alignas(16) signed char h8f[2][4096];  // fragment-ordered [q][kq16][row][e]
  __shared__ int effs_l[16], cnts_l[16];

  // load 16 anchors' order lists (coalesced), eff/cnt, zero h buffer 0
  for (int k=0;k<16;++k){
    int ii = k*512 + tid;
    int row = ii >> 9, idxo = ii & 511;
    int m = g*16 + row;
    ord_s[row][idxo] = (m < cntA) ? order[(size_t)(offA + m)*MAXT + idxo] : NN;
  }
  if (tid < 16){
    int m = g*16 + tid;
    int act = (m < cntA);
    int a = offA + m;
    cnts_l[tid] = act ? cnteff[2*a]   : 0;
    effs_l[tid] = act ? cnteff[2*a+1] : 0;
  }
  for (int k=tid; k<1024; k+=512) ((int*)h8f[0])[k] = 0;

  int c0 = w*32 + l15, c1 = c0 + 16;
  float bn0 = bhh[sd*G3 + 2*DD + c0], bn1 = bhh[sd*G3 + 2*DD + c1];
  const float ISQ = 1.f/(127.f*127.f);
  float sr0 = cm[sd*G3 +       c0]*ISQ, sr1 = cm[sd*G3 +       c1]*ISQ;
  float sz0 = cm[sd*G3 + 256 + c0]*ISQ, sz1 = cm[sd*G3 + 256 + c1]*ISQ;
  float sn0 = cm[sd*G3 + 512 + c0]*ISQ, sn1 = cm[sd*G3 + 512 + c1]*ISQ;

  v4i bf[6][4];
  {
    const v4i* wp = whhB8 + (((size_t)sd*8 + w)*64 + lane)*24;
    #pragma unroll
    for (int nt=0;nt<6;++nt)
      #pragma unroll
      for (int q=0;q<4;++q)
        bf[nt][q] = wp[nt*4+q];
  }

  __syncthreads();   // ord_s/effs/h8f[0] visible; also the race-fix barrier

  int eff[4], cnt[4];
  #pragma unroll
  for (int r=0;r<4;++r){ int row = g16*4+r; eff[r]=effs_l[row]; cnt[r]=cnts_l[row]; }
  int maxeff = 0;
  for (int m=0;m<16;++m) maxeff = max(maxeff, effs_l[m]);

  const uint2* Eb = reinterpret_cast<const uint2*>(E) + (size_t)sd*NNP*256;

  float h[8];
  #pragma unroll
  for (int i=0;i<8;++i) h[i]=0.f;

  uint2 gA[8], gB[8];
  #pragma unroll
  for (int r=0;r<4;++r){
    int n = NN;
    if (0 < eff[r]){
      int idx = d ? (eff[r]-1) : 0;
      n = (idx < cnt[r]) ? ord_s[g16*4+r][idx] : NN;
    }
    gA[2*r]   = Eb[(size_t)n*256 + c0];
    gA[2*r+1] = Eb[(size_t)n*256 + c1];
  }
  #pragma unroll
  for (int i=0;i<8;++i) gB[i] = gA[i];

  int wbase = (w>>1)*1024 + (w&1)*512 + l15;

#define GRU_STEP(T, HBIN, HBOUT, GCUR, GNXT)                                      \
  {                                                                               \
    if ((T)+1 < maxeff){                                                          \
      _Pragma("unroll")                                                           \
      for (int r=0;r<4;++r){                                                      \
        int tn = (T)+1, n = NN;                                                   \
        if (tn < eff[r]){                                                         \
          int idx = d ? (eff[r]-1-tn) : tn;                                       \
          n = (idx < cnt[r]) ? ord_s[g16*4+r][idx] : NN;                          \
        }                                                                         \
        GNXT[2*r]   = Eb[(size_t)n*256 + c0];                                     \
        GNXT[2*r+1] = Eb[(size_t)n*256 + c1];                                     \
      }                                                                           \
    }                                                                             \
    v4i acc0={0,0,0,0}, acc1={0,0,0,0}, acc2={0,0,0,0};                           \
    v4i acc3={0,0,0,0}, acc4={0,0,0,0}, acc5={0,0,0,0};                           \
    _Pragma("unroll")                                                             \
    for (int q=0;q<4;++q){                                                        \
      v4i af = *reinterpret_cast<const v4i*>(HBIN + q*1024 + lane*16);            \
      acc0 = __builtin_amdgcn_mfma_i32_16x16x64_i8(af, bf[0][q], acc0, 0,0,0);    \
      acc1 = __builtin_amdgcn_mfma_i32_16x16x64_i8(af, bf[1][q], acc1, 0,0,0);    \
      acc2 = __builtin_amdgcn_mfma_i32_16x16x64_i8(af, bf[2][q], acc2, 0,0,0);    \
      acc3 = __builtin_amdgcn_mfma_i32_16x16x64_i8(af, bf[3][q], acc3, 0,0,0);    \
      acc4 = __builtin_amdgcn_mfma_i32_16x16x64_i8(af, bf[4][q], acc4, 0,0,0);    \
      acc5 = __builtin_amdgcn_mfma_i32_16x16x64_i8(af, bf[5][q], acc5, 0,0,0);    \
    }                                                                             \
    _Pragma("unroll")                                                             \
    for (int r=0;r<4;++r){                                                        \
      v4h e0 = __builtin_bit_cast(v4h, GCUR[2*r]);                                \
      v4h e1 = __builtin_bit_cast(v4h, GCUR[2*r+1]);                              \
      bool upd = ((T) < eff[r]);                                                  \
      float rr0 = sigf((float)e0[0] + (float)acc0[r]*sr0);                        \
      float zz0 = sigf((float)e0[1] + (float)acc2[r]*sz0);                        \
      float nv0 = tanhf_fast((float)e0[2] + rr0*((float)acc4[r]*sn0 + bn0));      \
      float hn0 = zz0*(h[2*r]-nv0)+nv0;                                           \
      h[2*r] = upd ? hn0 : h[2*r];                                                \
      HBOUT[wbase + (g16*4+r)*16] = (signed char)(int)rintf(h[2*r]*127.f);        \
      float rr1 = sigf((float)e1[0] + (float)acc1[r]*sr1);                        \
      float zz1 = sigf((float)e1[1] + (float)acc3[r]*sz1);                        \
      float nv1 = tanhf_fast((float)e1[2] + rr1*((float)acc5[r]*sn1 + bn1));      \
      float hn1 = zz1*(h[2*r+1]-nv1)+nv1;                                         \
      h[2*r+1] = upd ? hn1 : h[2*r+1];                                            \
      HBOUT[wbase + 256 + (g16*4+r)*16] = (signed char)(int)rintf(h[2*r+1]*127.f);\
    }                                                                             \
    __syncthreads();                                                              \
  }

  for (int t2=0; t2<maxeff; t2+=2){
    GRU_STEP(t2,   h8f[0], h8f[1], gA, gB)
    if (t2+1 < maxeff)
      GRU_STEP(t2+1, h8f[1], h8f[0], gB, gA)
  }
#undef GRU_STEP

  #pragma unroll
  for (int r=0;r<4;++r){
    int m = g*16 + g16*4 + r;
    if (m < cntA){
      int a = offA + m;
      hout[(size_t)(2*a+d)*DD + c0] = h[2*r];
      hout[(size_t)(2*a+d)*DD + c1] = h[2*r+1];
    }
  }
}

// ================= MLP via MFMA fp16 (unchanged from round 14) =================
__global__ __launch_bounds__(512) void mlp_kernel(
    const float* __restrict__ hout, const float* __restrict__ abn,
    const float* __restrict__ anchors, const float* __restrict__ audio_len,
    const v8h* __restrict__ w1F, const v8h* __restrict__ w2F, const v8h* __restrict__ w3F,
    const float* __restrict__ qs,
    const float* __restrict__ sw0, const float* __restrict__ ew0,
    const float* __restrict__ sw1, const float* __restrict__ ew1,
    const float* __restrict__ sw2, const float* __restrict__ ew2,
    float* __restrict__ out){
  int bm = blockIdx.x;
  int si = (bm==0)?0:((bm<4)?1:2);
  int mt = (bm==0)?0:((bm<4)?(bm-1):0);
  int cntA = (si==1)?40:15;
  int offA = (si==0)?0:((si==1)?15:55);
  int bb   = (si==1)?60:80;
  int m0 = mt*16;
  const float* sw = (si==0)?sw0:((si==1)?sw1:sw2);
  const float* ew = (si==0)?ew0:((si==1)?ew1:ew2);
  float al = audio_len[0];

  __shared__ _Float16 feat[16][552];
  __shared__ _Float16 h1s[16][264];
  __shared__ float    os[16][184];

  int tid = threadIdx.x;
  int lane = tid & 63, wv = tid >> 6;
  int l15 = lane & 15, g16 = lane >> 4;

  for (int idx = tid; idx < 16*552; idx += 512){
    int r = idx / 552, c2 = idx - r*552;
    float v = 0.f;
    int m = m0 + r;
    if (m < cntA){
      int a = offA + m;
      if (c2 < 256)       v = hout[(size_t)(2*a)*DD + c2];
      else if (c2 < 512)  v = hout[(size_t)(2*a+1)*DD + (c2-256)];
      else if (c2 == 512) v = abn[m];
      else if (c2 == 513){ float s=anchors[2*a], e=anchors[2*a+1]; v = (s+e)*0.5f/al; }
      else if (c2 == 514){ float s=anchors[2*a], e=anchors[2*a+1]; v = (e-s)/al; }
    }
    feat[r][c2] = (_Float16)v;
  }
  __syncthreads();
  float sc1 = qs[si], sc2 = qs[3+si], sc3 = qs[6+si];

  for (int nt = wv; nt < 16; nt += 8){
    int j = nt*16 + l15;
    const v8h* bp = w1F + (size_t)(si*16 + nt)*17*64 + lane;
    v4f acc = {0.f,0.f,0.f,0.f};
    for (int kq = 0; kq < 17; ++kq){
      v8h af = *reinterpret_cast<const v8h*>(&feat[l15][kq*32 + 8*g16]);
      acc = __builtin_amdgcn_mfma_f32_16x16x32_f16(af, bp[kq*64], acc, 0,0,0);
    }
    #pragma unroll
    for (int r=0;r<4;++r) h1s[g16*4+r][j] = (_Float16)fmaxf(acc[r]*sc1, 0.f);
  }
  __syncthreads();
  for (int nt = wv; nt < 16; nt += 8){
    int j = nt*16 + l15;
    const v8h* bp = w2F + (size_t)(si*16 + nt)*8*64 + lane;
    v4f acc = {0.f,0.f,0.f,0.f};
    for (int kq = 0; kq < 8; ++kq){
      v8h af = *reinterpret_cast<const v8h*>(&h1s[l15][kq*32 + 8*g16]);
      acc = __builtin_amdgcn_mfma_f32_16x16x32_f16(af, bp[kq*64], acc, 0,0,0);
    }
    #pragma unroll
    for (int r=0;r<4;++r) feat[g16*4+r][j] = (_Float16)fmaxf(acc[r]*sc2, 0.f);
  }
  __syncthreads();
  for (int nt = wv; nt < 11; nt += 8){
    int j = nt*16 + l15;
    const v8h* bp = w3F + (size_t)(si*11 + nt)*8*64 + lane;
    v4f acc = {0.f,0.f,0.f,0.f};
    for (int kq = 0; kq < 8; ++kq){
      v8h af = *reinterpret_cast<const v8h*>(&feat[l15][kq*32 + 8*g16]);
      acc = __builtin_amdgcn_mfma_f32_16x16x32_f16(af, bp[kq*64], acc, 0,0,0);
    }
    #pragma unroll
    for (int r=0;r<4;++r) os[g16*4+r][j] = acc[r]*sc3;
  }
  __syncthreads();
  for (int lm = wv; lm < 16; lm += 8){
    int m = m0 + lm;
    if (m >= cntA) continue;
    int a = offA + m;
    float s = anchors[2*a], e = anchors[2*a+1];
    float x0 = (lane < bb) ? os[lm][lane] : -1e30f;
    float x1 = (lane+64 < bb) ? os[lm][lane+64] : -1e30f;
    float mx = fmaxf(x0, x1);
    #pragma unroll
    for (int sh=1; sh<64; sh<<=1) mx = fmaxf(mx, __shfl_xor(mx, sh));
    float e0 = (lane < bb) ? expf(x0-mx) : 0.f;
    float e1 = (lane+64 < bb) ? expf(x1-mx) : 0.f;
    float se = e0 + e1;
    float ws2 = e0*((lane<bb)?sw[lane]:0.f) + e1*((lane+64<bb)?sw[lane+64]:0.f);
    #pragma unroll
    for (int sh=1; sh<64; sh<<=1){ se += __shfl_xor(se, sh); ws2 += __shfl_xor(ws2, sh); }
    float so = ws2/se;
    float y0 = (lane < bb) ? os[lm][bb+lane] : -1e30f;
    float y1 = (lane+64 < bb) ? os[lm][bb+lane+64] : -1e30f;
    float my = fmaxf(y0, y1);
    #pragma unroll
    for (int sh=1; sh<64; sh<<=1) my = fmaxf(my, __shfl_xor(my, sh));
    float f0 = (lane < bb) ? expf(y0-my) : 0.f;
    float f1 = (lane+64 < bb) ? expf(y1-my) : 0.f;
    float sf = f0 + f1;
    float wf = f0*((lane<bb)?ew[lane]:0.f) + f1*((lane+64<bb)?ew[lane+64]:0.f);
    #pragma unroll
    for (int sh=1; sh<64; sh<<=1){ sf += __shfl_xor(sf, sh); wf += __shfl_xor(wf, sh); }
    float eo = wf/sf;
    if (lane == 0){
      out[2*a]   = fminf(fmaxf(s+so, 0.f), al);
      out[2*a+1] = fminf(fmaxf(e+eo, 0.f), al);
      out[140+a] = os[lm][2*bb];
    }
    if (lane < 4) out[210+4*a+lane] = os[lm][2*bb+1+lane];
  }
}

extern "C" void kernel_launch(void* const* d_in, const int* in_sizes, int n_in,
                              void* d_out, int out_size, void* d_ws, size_t ws_size,
                              hipStream_t stream){
  const float* emb   = (const float*)d_in[0];
  const float* tpin  = (const float*)d_in[1];
  const float* npred = (const float*)d_in[2];
  const float* alen  = (const float*)d_in[3];
  const float* anch  = (const float*)d_in[4];
  const float* wih   = (const float*)d_in[5];
  const float* whh   = (const float*)d_in[6];
  const float* bih   = (const float*)d_in[7];
  const float* bhh   = (const float*)d_in[8];
  const float* w1    = (const float*)d_in[9];
  const float* w2    = (const float*)d_in[10];
  const float* w30   = (const float*)d_in[11];
  const float* w31   = (const float*)d_in[12];
  const float* w32   = (const float*)d_in[13];
  const float* sw0   = (const float*)d_in[14];
  const float* ew0   = (const float*)d_in[15];
  const float* sw1   = (const float*)d_in[16];
  const float* ew1   = (const float*)d_in[17];
  const float* sw2   = (const float*)d_in[18];
  const float* ew2   = (const float*)d_in[19];

  char* ws = (char*)d_ws;
  size_t off = 0;
  auto take = [&](size_t bytes)->char*{
    char* p = ws + off;
    off = (off + bytes + 255) & ~(size_t)255;
    return p;
  };
  float* abn    = (float*)take((size_t)NN*4);
  int*   order_ = (int*)  take((size_t)NA*MAXT*4);
  int*   cnteff = (int*)  take((size_t)NA*2*4);
  float* qs     = (float*)take(16*4);
  float* cm     = (float*)take((size_t)6*G3*4);
  uint4* whhB8  = (uint4*)take((size_t)6*8*1536*16);
  _Float16* E   = (_Float16*)take((size_t)6*NNP*1024*2);
  float* hout   = (float*)take((size_t)NA*2*DD*4);
  v8h* w1F      = (v8h*)take((size_t)NF1*16);
  v8h* w2F      = (v8h*)take((size_t)NF2*16);
  v8h* w3F      = (v8h*)take((size_t)NF3*16);
  (void)ws_size; (void)in_sizes; (void)n_in; (void)out_size;

  mega_kernel<<<dim3(725), dim3(256), 0, stream>>>(npred, tpin, alen, anch, whh, wih, emb,
                                                   bih, bhh, w1, w2, w30, w31, w32,
                                                   abn, order_, cnteff, qs, cm, whhB8, E);
  {
    const int packBlocks = (NFT + 511)/512;   // 183
    gru_kernel<<<dim3(NGRU + packBlocks), dim3(512), 0, stream>>>(
        E, (const v4i*)whhB8, bhh, cm, order_, cnteff, hout,
        w1, w2, w30, w31, w32, qs, w1F, w2F, w3F);
  }
  mlp_kernel<<<dim3(5), dim3(512), 0, stream>>>(hout, abn, anch, alen, w1F, w2F, w3F, qs,
                                                sw0, ew0, sw1, ew1, sw2, ew2, (float*)d_out);
}

// Round 16
// 371.739 us; speedup vs baseline: 2.2407x; 2.2407x over previous
//
#include <hip/hip_runtime.h>
#include <math.h>

#define NN 1024
#define NNP 1025
#define DD 256
#define CC 5
#define G3 768
#define MAXT 512
#define NA 70

typedef _Float16 v8h __attribute__((ext_vector_type(8)));
typedef _Float16 v4h __attribute__((ext_vector_type(4)));
typedef float v4f __attribute__((ext_vector_type(4)));
typedef int v4i __attribute__((ext_vector_type(4)));

#define NF1 (3*16*17*64)
#define NF2 (3*16*8*64)
#define NF3 (3*11*8*64)
#define NFT (NF1+NF2+NF3)

__device__ __forceinline__ float sigf(float x){ return __fdividef(1.f, 1.f + __expf(-x)); }
__device__ __forceinline__ float tanhf_fast(float x){ return 1.f - __fdividef(2.f, __expf(2.f*x) + 1.f); }

// ================= MEGA kernel =================
// [0,4) abn ; [4,74) order ; [74,83) qs absmax ; [83,101) E bias row
// [101,149) whh colmax + int8 frags per (sd, w8)
// [149,725) E-GEMM: block = (sd, colgroup, rowoctet); B register-resident, 8 row-tiles
__global__ __launch_bounds__(256) void mega_kernel(
    const float* __restrict__ node_pred, const float* __restrict__ tp_in,
    const float* __restrict__ audio_len, const float* __restrict__ anchors,
    const float* __restrict__ whh, const float* __restrict__ wih,
    const float* __restrict__ emb,
    const float* __restrict__ bih, const float* __restrict__ bhh,
    const float* __restrict__ w1, const float* __restrict__ w2,
    const float* __restrict__ w30, const float* __restrict__ w31, const float* __restrict__ w32,
    float* __restrict__ abn, int* __restrict__ order, int* __restrict__ cnteff,
    float* __restrict__ qs, float* __restrict__ cm,
    uint4* __restrict__ whhB8, _Float16* __restrict__ E){
  __shared__ __align__(16) unsigned char smem[16*264*2];
  int b = blockIdx.x, tid = threadIdx.x;
  if (b < 4){
    int i = b*256 + tid;
    float pv[CC]; float m = -1e30f;
    for (int c=0;c<CC;++c){ pv[c]=node_pred[i*CC+c]; m=fmaxf(m,pv[c]); }
    float s=0.f;
    for (int c=0;c<CC;++c) s += expf(pv[c]-m);
    abn[i] = expf(pv[0]-m)/s;
  } else if (b < 74){
    if (tid >= 64) return;
    int a = b-4; int lane = tid;
    float al = audio_len[0];
    float s = anchors[2*a], e = anchors[2*a+1];
    int* ord = order + a*MAXT;
    int cnt = 0;
    for (int base=0; base<NN; base+=64){
      float tp = tp_in[base+lane]*al;
      bool msk = (tp>=s)&&(tp<=e);
      unsigned long long bal = __ballot(msk);
      int off = (int)__popcll(bal & ((1ull<<lane)-1ull));
      if (msk && (cnt+off)<MAXT) ord[cnt+off] = base+lane;
      cnt += (int)__popcll(bal);
    }
    if (lane==0){ int c = cnt<MAXT?cnt:MAXT; cnteff[2*a]=c; cnteff[2*a+1]=(c>0)?c:1; }
  } else if (b < 83){
    int m = b-74;
    const float* p; int n;
    if (m<3){ p = w1 + (size_t)m*256*519; n = 256*519; }
    else if (m<6){ p = w2 + (size_t)(m-3)*256*256; n = 256*256; }
    else { p = (m==6)?w30:((m==7)?w31:w32); n = ((m==7)?125:165)*256; }
    float mx = 0.f;
    for (int i=tid;i<n;i+=256) mx = fmaxf(mx, fabsf(p[i]));
    float* red = (float*)smem;
    red[tid]=mx; __syncthreads();
    for (int sft=128; sft>0; sft>>=1){ if (tid<sft) red[tid]=fmaxf(red[tid],red[tid+sft]); __syncthreads(); }
    if (tid==0) qs[m] = fmaxf(red[0]/127.f, 1e-8f);
  } else if (b < 101){
    int i = (b-83)*256 + tid;
    if (i >= 4608) return;
    int gt = i % 3; int c = (i/3)&255; int sd = i/768;
    int j = gt*256 + c;
    float v = bih[sd*G3+j] + ((gt<2)? bhh[sd*G3+j] : 0.f);
    E[((size_t)(sd*NNP + NN))*1024 + c*4 + gt] = (_Float16)v;
  } else if (b < 149){
    // whh colmax + int8 fragment pack per (sd, w), 8-wave gru layout (6 n-tiles)
    int bb = b-101;
    int sd = bb>>3, w = bb&7;
    float* cm_lds = (float*)smem;         // 96 floats
    int lane = tid & 63, wv = tid >> 6;
    for (int it=0; it<24; ++it){
      int lr = it*4 + wv;                 // 0..95
      int gt = lr>>5, c = lr&31;
      int j = gt*256 + w*32 + c;
      float4 v = reinterpret_cast<const float4*>(whh + ((size_t)sd*G3 + j)*DD)[lane];
      float mx = fmaxf(fmaxf(fabsf(v.x),fabsf(v.y)), fmaxf(fabsf(v.z),fabsf(v.w)));
      #pragma unroll
      for (int sh=1; sh<64; sh<<=1) mx = fmaxf(mx, __shfl_xor(mx, sh));
      if (lane==0){
        float cmax = fmaxf(mx, 1e-12f);
        cm_lds[lr] = cmax;
        cm[sd*G3 + j] = cmax;
      }
    }
    __syncthreads();
    #pragma unroll
    for (int ee=0; ee<6; ++ee){
      int il = tid*6 + ee;                // 0..1535 = lane2*24 + nt*4 + q
      int q    = il & 3;
      int nt   = (il>>2) % 6;
      int lane2= il / 24;
      int gt = nt>>1, half = nt&1;
      int j  = gt*256 + w*32 + half*16 + (lane2&15);
      int lr = gt*32  + half*16 + (lane2&15);
      int kbase = 64*q + 16*(lane2>>4);
      float inv = 127.f/cm_lds[lr];
      const float* src = whh + ((size_t)sd*G3 + j)*DD + kbase;
      unsigned int dw[4];
      #pragma unroll
      for (int d2=0; d2<4; ++d2){
        unsigned int acc = 0;
        #pragma unroll
        for (int e2=0; e2<4; ++e2){
          float qv = rintf(src[4*d2+e2]*inv);
          qv = fminf(fmaxf(qv,-127.f),127.f);
          int iq = (int)qv;
          acc |= ((unsigned int)(iq & 255)) << (8*e2);
        }
        dw[d2] = acc;
      }
      uint4 v; v.x=dw[0]; v.y=dw[1]; v.z=dw[2]; v.w=dw[3];
      whhB8[(size_t)(sd*8 + w)*1536 + il] = v;
    }
  } else {
    // E-GEMM: block = (sd, colgroup cg, rowoctet rq). B fp16 fragments live in
    // registers (converted once); loop 8 row-tiles staging A in LDS.
    typedef _Float16 AsT[264];
    AsT* As = (AsT*)smem;
    int b2 = b - 149;                    // 0..575
    int sd = b2 / 96;
    int rem = b2 - sd*96;
    int cg = rem >> 3, rq = rem & 7;
    int lane = tid & 63, wv = tid >> 6;
    int l15 = lane & 15, g16 = lane >> 4;
    int c_t = cg*4 + wv;
    int j = c_t*16 + l15;
    const float* Bp = wih + ((size_t)sd*G3 + j)*DD + 8*g16;
    float bsum = bih[sd*G3 + j] + (((j>>8) < 2) ? bhh[sd*G3 + j] : 0.f);
    v8h bf[8];
    #pragma unroll
    for (int q=0;q<8;++q){
      float4 b0 = *reinterpret_cast<const float4*>(Bp + 32*q);
      float4 b1 = *reinterpret_cast<const float4*>(Bp + 32*q + 4);
      v8h o;
      o[0]=(_Float16)b0.x; o[1]=(_Float16)b0.y; o[2]=(_Float16)b0.z; o[3]=(_Float16)b0.w;
      o[4]=(_Float16)b1.x; o[5]=(_Float16)b1.y; o[6]=(_Float16)b1.z; o[7]=(_Float16)b1.w;
      bf[q] = o;
    }
    int gt = j>>8, cc = j&255;
    for (int rt8=0; rt8<8; ++rt8){
      int row0 = (rq*8 + rt8)*16;
      {
        int rr = tid>>4, k0 = (tid&15)*16;
        const float4* ep = reinterpret_cast<const float4*>(emb + (size_t)(row0+rr)*DD + k0);
        #pragma unroll
        for (int f=0; f<4; ++f){
          float4 v = ep[f];
          v4h o; o[0]=(_Float16)v.x; o[1]=(_Float16)v.y; o[2]=(_Float16)v.z; o[3]=(_Float16)v.w;
          *reinterpret_cast<v4h*>(&As[rr][k0 + f*4]) = o;
        }
      }
      __syncthreads();
      v4f acc = {0.f,0.f,0.f,0.f};
      #pragma unroll
      for (int q=0;q<8;++q){
        v8h af = *reinterpret_cast<const v8h*>(&As[l15][32*q + 8*g16]);
        acc = __builtin_amdgcn_mfma_f32_16x16x32_f16(af, bf[q], acc, 0,0,0);
      }
      #pragma unroll
      for (int r=0;r<4;++r){
        int row = row0 + g16*4 + r;
        E[((size_t)(sd*NNP + row))*1024 + cc*4 + gt] = (_Float16)(acc[r] + bsum);
      }
      __syncthreads();
    }
  }
}

// ================= GRU launch: blocks [0,140) GRU (8 waves) ; blocks >=140 MLP frag pack =================
__global__ __launch_bounds__(512, 2) void gru_kernel(
    const _Float16* __restrict__ E, const v4i* __restrict__ whhB8,
    const float* __restrict__ bhh, const float* __restrict__ cm,
    const int* __restrict__ order, const int* __restrict__ cnteff,
    float* __restrict__ hout,
    const float* __restrict__ w1, const float* __restrict__ w2,
    const float* __restrict__ w30, const float* __restrict__ w31, const float* __restrict__ w32,
    const float* __restrict__ qs,
    v8h* __restrict__ w1F, v8h* __restrict__ w2F, v8h* __restrict__ w3F){
  int blk = blockIdx.x;
  int tid = threadIdx.x;
  if (blk >= NA*2){
    int i = (blk - NA*2)*512 + tid;
    if (i < NF1){
      int lane = i & 63; int rest = i >> 6;
      int q = rest % 17; int rc = rest / 17;
      int ct = rc & 15; int si = rc >> 4;
      int j = ct*16 + (lane&15);
      int k0 = q*32 + 8*(lane>>4);
      float inv = 1.f/qs[si];
      const float* src = w1 + ((size_t)(si*256 + j))*519;
      v8h o;
      #pragma unroll
      for (int e=0;e<8;++e){
        int k = k0+e;
        float wv = (k<519)? src[k] : 0.f;
        float qv = rintf(wv*inv);
        qv = fminf(fmaxf(qv,-128.f),127.f);
        o[e] = (_Float16)qv;
      }
      w1F[i] = o;
    } else if (i < NF1+NF2){
      int r = i - NF1;
      int lane = r & 63; int rest = r >> 6;
      int q = rest & 7; int rc = rest >> 3;
      int ct = rc & 15; int si = rc >> 4;
      int j = ct*16 + (lane&15);
      int k0 = q*32 + 8*(lane>>4);
      float inv = 1.f/qs[3+si];
      const float* src = w2 + ((size_t)(si*256 + j))*256 + k0;
      v8h o;
      #pragma unroll
      for (int e=0;e<8;++e){
        float qv = rintf(src[e]*inv);
        qv = fminf(fmaxf(qv,-128.f),127.f);
        o[e] = (_Float16)qv;
      }
      w2F[r] = o;
    } else if (i < NFT){
      int r = i - NF1 - NF2;
      int lane = r & 63; int rest = r >> 6;
      int q = rest & 7; int rc = rest >> 3;
      int ct = rc % 11; int si = rc / 11;
      int j = ct*16 + (lane&15);
      int nout = (si==1)?125:165;
      const float* w3 = (si==0)?w30:((si==1)?w31:w32);
      int k0 = q*32 + 8*(lane>>4);
      float inv = 1.f/qs[6+si];
      v8h o;
      #pragma unroll
      for (int e=0;e<8;++e){
        float wv = (j<nout)? w3[(size_t)j*256 + k0+e] : 0.f;
        float qv = rintf(wv*inv);
        qv = fminf(fmaxf(qv,-128.f),127.f);
        o[e] = (_Float16)qv;
      }
      w3F[r] = o;
    }
    return;
  }
  // ---- GRU proper: 8 waves, wave w owns cells [w*32, w*32+32) as 6 n-tiles ----
  int a = blk>>1, d = blk&1;
  int si = (a<15)?0:((a<55)?1:2);
  int sd = si*2+d;
  int w = tid>>6, lane = tid&63;
  int g16 = lane>>4;
  int ct = g16 & 1;

  __shared__ int ord_s[MAXT];
  __shared__ alignas(16) signed char h8[2][DD];

  ord_s[tid] = order[a*MAXT + tid];
  if (tid < DD) h8[0][tid] = 0;

  int cnt = cnteff[2*a], eff = cnteff[2*a+1];

  int c = w*32 + (lane&31);
  float bn = bhh[sd*G3 + 2*DD + c];
  const float ISQ = 1.f/(127.f*127.f);
  float sr = cm[sd*G3 +        c]*ISQ;
  float sz = cm[sd*G3 + 256 +  c]*ISQ;
  float sn = cm[sd*G3 + 512 +  c]*ISQ;

  v4i bf[6][4];
  {
    const v4i* wp = whhB8 + (((size_t)sd*8 + w)*64 + lane)*24;
    #pragma unroll
    for (int nt=0;nt<6;++nt)
      #pragma unroll
      for (int q=0;q<4;++q)
        bf[nt][q] = wp[nt*4+q];
  }

  const uint2* Eb = reinterpret_cast<const uint2*>(E) + (size_t)sd*NNP*256;

  // RACE FIX: barrier BEFORE any read of ord_s.
  __syncthreads();

  float h = 0.f;
  uint2 gEven, gOdd;
  {
    int idx0 = d ? (eff-1) : 0;
    int n0 = (idx0 < cnt) ? ord_s[idx0] : NN;
    gEven = Eb[(size_t)n0*256 + c];
  }

  for (int t=0;t<eff;++t){
    int p = t & 1;
    if (t+1 < eff){
      int idx1 = d ? (eff-2-t) : (t+1);
      int n1 = (idx1 < cnt) ? ord_s[idx1] : NN;
      if (p==0) gOdd  = Eb[(size_t)n1*256 + c];
      else      gEven = Eb[(size_t)n1*256 + c];
    }
    v4i acc0={0,0,0,0}, acc1={0,0,0,0}, acc2={0,0,0,0};
    v4i acc3={0,0,0,0}, acc4={0,0,0,0}, acc5={0,0,0,0};
    #pragma unroll
    for (int q=0;q<4;++q){
      v4i af = *reinterpret_cast<const v4i*>(&h8[p][64*q + 16*g16]);
      acc0 = __builtin_amdgcn_mfma_i32_16x16x64_i8(af, bf[0][q], acc0, 0,0,0);
      acc1 = __builtin_amdgcn_mfma_i32_16x16x64_i8(af, bf[1][q], acc1, 0,0,0);
      acc2 = __builtin_amdgcn_mfma_i32_16x16x64_i8(af, bf[2][q], acc2, 0,0,0);
      acc3 = __builtin_amdgcn_mfma_i32_16x16x64_i8(af, bf[3][q], acc3, 0,0,0);
      acc4 = __builtin_amdgcn_mfma_i32_16x16x64_i8(af, bf[4][q], acc4, 0,0,0);
      acc5 = __builtin_amdgcn_mfma_i32_16x16x64_i8(af, bf[5][q], acc5, 0,0,0);
    }
    v4h ev = __builtin_bit_cast(v4h, (p==0) ? gEven : gOdd);
    int ir  = (ct==0) ? acc0[0] : acc1[0];
    int iz  = (ct==0) ? acc2[0] : acc3[0];
    int inn = (ct==0) ? acc4[0] : acc5[0];
    float r  = sigf((float)ev[0] + (float)ir*sr);
    float z  = sigf((float)ev[1] + (float)iz*sz);
    float nv = tanhf_fast((float)ev[2] + r*((float)inn*sn + bn));
    h = z*(h - nv) + nv;
    if (lane < 32) h8[p^1][c] = (signed char)(int)rintf(h*127.f);
    __syncthreads();
  }
  if (lane < 32) hout[(size_t)(2*a+d)*DD + c] = h;
}

// ================= MLP via MFMA fp16, pre-packed quantized fragments =================
__global__ __launch_bounds__(512) void mlp_kernel(
    const float* __restrict__ hout, const float* __restrict__ abn,
    const float* __restrict__ anchors, const float* __restrict__ audio_len,
    const v8h* __restrict__ w1F, const v8h* __restrict__ w2F, const v8h* __restrict__ w3F,
    const float* __restrict__ qs,
    const float* __restrict__ sw0, const float* __restrict__ ew0,
    const float* __restrict__ sw1, const float* __restrict__ ew1,
    const float* __restrict__ sw2, const float* __restrict__ ew2,
    float* __restrict__ out){
  int bm = blockIdx.x;
  int si = (bm==0)?0:((bm<4)?1:2);
  int mt = (bm==0)?0:((bm<4)?(bm-1):0);
  int cntA = (si==1)?40:15;
  int offA = (si==0)?0:((si==1)?15:55);
  int bb   = (si==1)?60:80;
  int m0 = mt*16;
  const float* sw = (si==0)?sw0:((si==1)?sw1:sw2);
  const float* ew = (si==0)?ew0:((si==1)?ew1:ew2);
  float al = audio_len[0];

  __shared__ _Float16 feat[16][552];
  __shared__ _Float16 h1s[16][264];
  __shared__ float    os[16][184];

  int tid = threadIdx.x;
  int lane = tid & 63, wv = tid >> 6;
  int l15 = lane & 15, g16 = lane >> 4;

  for (int idx = tid; idx < 16*552; idx += 512){
    int r = idx / 552, c2 = idx - r*552;
    float v = 0.f;
    int m = m0 + r;
    if (m < cntA){
      int a = offA + m;
      if (c2 < 256)       v = hout[(size_t)(2*a)*DD + c2];
      else if (c2 < 512)  v = hout[(size_t)(2*a+1)*DD + (c2-256)];
      else if (c2 == 512) v = abn[m];
      else if (c2 == 513){ float s=anchors[2*a], e=anchors[2*a+1]; v = (s+e)*0.5f/al; }
      else if (c2 == 514){ float s=anchors[2*a], e=anchors[2*a+1]; v = (e-s)/al; }
    }
    feat[r][c2] = (_Float16)v;
  }
  __syncthreads();
  float sc1 = qs[si], sc2 = qs[3+si], sc3 = qs[6+si];

  for (int nt = wv; nt < 16; nt += 8){
    int j = nt*16 + l15;
    const v8h* bp = w1F + (size_t)(si*16 + nt)*17*64 + lane;
    v4f acc = {0.f,0.f,0.f,0.f};
    for (int kq = 0; kq < 17; ++kq){
      v8h af = *reinterpret_cast<const v8h*>(&feat[l15][kq*32 + 8*g16]);
      acc = __builtin_amdgcn_mfma_f32_16x16x32_f16(af, bp[kq*64], acc, 0,0,0);
    }
    #pragma unroll
    for (int r=0;r<4;++r) h1s[g16*4+r][j] = (_Float16)fmaxf(acc[r]*sc1, 0.f);
  }
  __syncthreads();
  for (int nt = wv; nt < 16; nt += 8){
    int j = nt*16 + l15;
    const v8h* bp = w2F + (size_t)(si*16 + nt)*8*64 + lane;
    v4f acc = {0.f,0.f,0.f,0.f};
    for (int kq = 0; kq < 8; ++kq){
      v8h af = *reinterpret_cast<const v8h*>(&h1s[l15][kq*32 + 8*g16]);
      acc = __builtin_amdgcn_mfma_f32_16x16x32_f16(af, bp[kq*64], acc, 0,0,0);
    }
    #pragma unroll
    for (int r=0;r<4;++r) feat[g16*4+r][j] = (_Float16)fmaxf(acc[r]*sc2, 0.f);
  }
  __syncthreads();
  for (int nt = wv; nt < 11; nt += 8){
    int j = nt*16 + l15;
    const v8h* bp = w3F + (size_t)(si*11 + nt)*8*64 + lane;
    v4f acc = {0.f,0.f,0.f,0.f};
    for (int kq = 0; kq < 8; ++kq){
      v8h af = *reinterpret_cast<const v8h*>(&feat[l15][kq*32 + 8*g16]);
      acc = __builtin_amdgcn_mfma_f32_16x16x32_f16(af, bp[kq*64], acc, 0,0,0);
    }
    #pragma unroll
    for (int r=0;r<4;++r) os[g16*4+r][j] = acc[r]*sc3;
  }
  __syncthreads();
  for (int lm = wv; lm < 16; lm += 8){
    int m = m0 + lm;
    if (m >= cntA) continue;
    int a = offA + m;
    float s = anchors[2*a], e = anchors[2*a+1];
    float x0 = (lane < bb) ? os[lm][lane] : -1e30f;
    float x1 = (lane+64 < bb) ? os[lm][lane+64] : -1e30f;
    float mx = fmaxf(x0, x1);
    #pragma unroll
    for (int sh=1; sh<64; sh<<=1) mx = fmaxf(mx, __shfl_xor(mx, sh));
    float e0 = (lane < bb) ? expf(x0-mx) : 0.f;
    float e1 = (lane+64 < bb) ? expf(x1-mx) : 0.f;
    float se = e0 + e1;
    float ws2 = e0*((lane<bb)?sw[lane]:0.f) + e1*((lane+64<bb)?sw[lane+64]:0.f);
    #pragma unroll
    for (int sh=1; sh<64; sh<<=1){ se += __shfl_xor(se, sh); ws2 += __shfl_xor(ws2, sh); }
    float so = ws2/se;
    float y0 = (lane < bb) ? os[lm][bb+lane] : -1e30f;
    float y1 = (lane+64 < bb) ? os[lm][bb+lane+64] : -1e30f;
    float my = fmaxf(y0, y1);
    #pragma unroll
    for (int sh=1; sh<64; sh<<=1) my = fmaxf(my, __shfl_xor(my, sh));
    float f0 = (lane < bb) ? expf(y0-my) : 0.f;
    float f1 = (lane+64 < bb) ? expf(y1-my) : 0.f;
    float sf = f0 + f1;
    float wf = f0*((lane<bb)?ew[lane]:0.f) + f1*((lane+64<bb)?ew[lane+64]:0.f);
    #pragma unroll
    for (int sh=1; sh<64; sh<<=1){ sf += __shfl_xor(sf, sh); wf += __shfl_xor(wf, sh); }
    float eo = wf/sf;
    if (lane == 0){
      out[2*a]   = fminf(fmaxf(s+so, 0.f), al);
      out[2*a+1] = fminf(fmaxf(e+eo, 0.f), al);
      out[140+a] = os[lm][2*bb];
    }
    if (lane < 4) out[210+4*a+lane] = os[lm][2*bb+1+lane];
  }
}

extern "C" void kernel_launch(void* const* d_in, const int* in_sizes, int n_in,
                              void* d_out, int out_size, void* d_ws, size_t ws_size,
                              hipStream_t stream){
  const float* emb   = (const float*)d_in[0];
  const float* tpin  = (const float*)d_in[1];
  const float* npred = (const float*)d_in[2];
  const float* alen  = (const float*)d_in[3];
  const float* anch  = (const float*)d_in[4];
  const float* wih   = (const float*)d_in[5];
  const float* whh   = (const float*)d_in[6];
  const float* bih   = (const float*)d_in[7];
  const float* bhh   = (const float*)d_in[8];
  const float* w1    = (const float*)d_in[9];
  const float* w2    = (const float*)d_in[10];
  const float* w30   = (const float*)d_in[11];
  const float* w31   = (const float*)d_in[12];
  const float* w32   = (const float*)d_in[13];
  const float* sw0   = (const float*)d_in[14];
  const float* ew0   = (const float*)d_in[15];
  const float* sw1   = (const float*)d_in[16];
  const float* ew1   = (const float*)d_in[17];
  const float* sw2   = (const float*)d_in[18];
  const float* ew2   = (const float*)d_in[19];

  char* ws = (char*)d_ws;
  size_t off = 0;
  auto take = [&](size_t bytes)->char*{
    char* p = ws + off;
    off = (off + bytes + 255) & ~(size_t)255;
    return p;
  };
  float* abn    = (float*)take((size_t)NN*4);
  int*   order_ = (int*)  take((size_t)NA*MAXT*4);
  int*   cnteff = (int*)  take((size_t)NA*2*4);
  float* qs     = (float*)take(16*4);
  float* cm     = (float*)take((size_t)6*G3*4);
  uint4* whhB8  = (uint4*)take((size_t)6*8*1536*16);
  _Float16* E   = (_Float16*)take((size_t)6*NNP*1024*2);
  float* hout   = (float*)take((size_t)NA*2*DD*4);
  v8h* w1F      = (v8h*)take((size_t)NF1*16);
  v8h* w2F      = (v8h*)take((size_t)NF2*16);
  v8h* w3F      = (v8h*)take((size_t)NF3*16);
  (void)ws_size; (void)in_sizes; (void)n_in; (void)out_size;

  mega_kernel<<<dim3(725), dim3(256), 0, stream>>>(npred, tpin, alen, anch, whh, wih, emb,
                                                   bih, bhh, w1, w2, w30, w31, w32,
                                                   abn, order_, cnteff, qs, cm, whhB8, E);
  {
    const int packBlocks = (NFT + 511)/512;   // 183
    gru_kernel<<<dim3(NA*2 + packBlocks), dim3(512), 0, stream>>>(
        E, (const v4i*)whhB8, bhh, cm, order_, cnteff, hout,
        w1, w2, w30, w31, w32, qs, w1F, w2F, w3F);
  }
  mlp_kernel<<<dim3(5), dim3(512), 0, stream>>>(hout, abn, anch, alen, w1F, w2F, w3F, qs,
                                                sw0, ew0, sw1, ew1, sw2, ew2, (float*)d_out);
}